// Round 1
// baseline (665.816 us; speedup 1.0000x reference)
//
#include <hip/hip_runtime.h>
#include <stdint.h>

// ---------------------------------------------------------------------------
// GCN 3-layer forward, MI355X. Round 1: correctness-first full implementation.
//
// Structure per layer l=1,2:
//   hws = (h @ Wl) * dinv[row]            (k_gemm<0>, scale fused)
//   out[t] = dinv[t]*(sum_{s in N(t)} hws[s] + hws[t]) + bl   (k_agg, CSR)
//   h' = relu(dropout(out))               (fused in k_agg, threefry inline)
// layer 3: d_out = h2 @ W3 + b3           (k_gemm<1>)
//
// Dropout masks reproduce JAX threefry with jax_threefry_partitionable=True:
//   split: child i = enc(key, (0, i)) (both words)  ["foldlike" split]
//   bits(j) = w0 ^ w1 of enc(childkey, (0, j));  keep = u(bits) < 0.8
// ---------------------------------------------------------------------------

__device__ __host__ __forceinline__ uint32_t tf_rotl(uint32_t v, int r) {
  return (v << r) | (v >> (32 - r));
}

__device__ __host__ __forceinline__ void threefry2x32(uint32_t k0, uint32_t k1,
                                                      uint32_t x0, uint32_t x1,
                                                      uint32_t& o0, uint32_t& o1) {
  const uint32_t k2 = k0 ^ k1 ^ 0x1BD11BDAu;
  x0 += k0; x1 += k1;
#define TFR(r) { x0 += x1; x1 = tf_rotl(x1, r); x1 ^= x0; }
  TFR(13) TFR(15) TFR(26) TFR(6)
  x0 += k1; x1 += k2 + 1u;
  TFR(17) TFR(29) TFR(16) TFR(24)
  x0 += k2; x1 += k0 + 2u;
  TFR(13) TFR(15) TFR(26) TFR(6)
  x0 += k0; x1 += k1 + 3u;
  TFR(17) TFR(29) TFR(16) TFR(24)
  x0 += k1; x1 += k2 + 4u;
  TFR(13) TFR(15) TFR(26) TFR(6)
  x0 += k2; x1 += k0 + 5u;
#undef TFR
  o0 = x0; o1 = x1;
}

// keep-flag for element j under partitionable threefry: bits = w0^w1 of enc(0,j)
__device__ __forceinline__ bool drop_keep(uint32_t k0, uint32_t k1, uint32_t j) {
  uint32_t a, b;
  threefry2x32(k0, k1, 0u, j, a, b);
  uint32_t bits = a ^ b;
  float u = __uint_as_float((bits >> 9) | 0x3f800000u) - 1.0f;
  return u < 0.8f;
}

// ------------------------- CSR build -------------------------
__global__ void k_hist(const int* __restrict__ tgt, int* __restrict__ cnt, int E) {
  int e = blockIdx.x * 256 + threadIdx.x;
  if (e < E) atomicAdd(&cnt[tgt[e]], 1);
}

// single block, 256 threads: exclusive scan of cnt -> row_start, plus dinv
__global__ void k_scan(const int* __restrict__ cnt, int* __restrict__ row_start,
                       float* __restrict__ dinv, int n) {
  const int T = 256;
  int tid = threadIdx.x;
  int chunk = (n + T - 1) / T;
  int lo = tid * chunk;
  int hi = min(lo + chunk, n);
  int sum = 0;
  for (int i = lo; i < hi; ++i) sum += cnt[i];
  __shared__ int part[T];
  __shared__ int excl[T + 1];
  part[tid] = sum;
  __syncthreads();
  if (tid == 0) {
    int a = 0;
    for (int i = 0; i < T; ++i) { excl[i] = a; a += part[i]; }
    excl[T] = a;
  }
  __syncthreads();
  int run = excl[tid];
  for (int i = lo; i < hi; ++i) {
    row_start[i] = run;
    int c = cnt[i];
    run += c;
    dinv[i] = rsqrtf((float)(c + 1));  // +1: self-loop; deg >= 1 always
  }
  if (tid == T - 1) row_start[n] = excl[T];
}

__global__ void k_scatter(const int* __restrict__ src, const int* __restrict__ tgt,
                          const int* __restrict__ row_start, int* __restrict__ cursor,
                          int* __restrict__ csr_src, int E) {
  int e = blockIdx.x * 256 + threadIdx.x;
  if (e >= E) return;
  int t = tgt[e];
  int pos = atomicAdd(&cursor[t], 1);
  csr_src[row_start[t] + pos] = src[e];
}

// ------------------------- GEMM (fp32, 64x64x16 tile, 4x4 micro) -------------------------
// MODE 0: C[m][n] = acc * sb[m]        (row scale = dinv, pre-aggregation)
// MODE 1: C[m][n] = acc + sb[n]        (bias, final layer)
template <int MODE>
__global__ __launch_bounds__(256) void k_gemm(const float* __restrict__ A,
                                              const float* __restrict__ B,
                                              const float* __restrict__ sb,
                                              float* __restrict__ C,
                                              int M, int N, int K) {
  const int BM = 64, BN = 64, BK = 16;
  __shared__ float As[BK][BM + 4];  // +4 pad: 2-way-max bank aliasing on write, 16B-aligned rows
  __shared__ float Bs[BK][BN];
  int tid = threadIdx.x;
  int tx = tid & 15, ty = tid >> 4;
  int bm = blockIdx.x * BM, bn = blockIdx.y * BN;
  int la_k = tid & 15, la_m = tid >> 4;   // A-tile loader coords
  int lb_n = tid & 63, lb_k = tid >> 6;   // B-tile loader coords
  float acc[4][4] = {};

  for (int kk = 0; kk < K; kk += BK) {
#pragma unroll
    for (int i = 0; i < 4; ++i) {
      int row = bm + la_m + i * 16;
      As[la_k][la_m + i * 16] = (row < M) ? A[(size_t)row * K + kk + la_k] : 0.0f;
    }
#pragma unroll
    for (int i = 0; i < 4; ++i) {
      Bs[lb_k + i * 4][lb_n] = B[(size_t)(kk + lb_k + i * 4) * N + bn + lb_n];
    }
    __syncthreads();
#pragma unroll
    for (int k = 0; k < BK; ++k) {
      float4 a = *(const float4*)&As[k][ty * 4];
      float4 b = *(const float4*)&Bs[k][tx * 4];
      acc[0][0] += a.x * b.x; acc[0][1] += a.x * b.y; acc[0][2] += a.x * b.z; acc[0][3] += a.x * b.w;
      acc[1][0] += a.y * b.x; acc[1][1] += a.y * b.y; acc[1][2] += a.y * b.z; acc[1][3] += a.y * b.w;
      acc[2][0] += a.z * b.x; acc[2][1] += a.z * b.y; acc[2][2] += a.z * b.z; acc[2][3] += a.z * b.w;
      acc[3][0] += a.w * b.x; acc[3][1] += a.w * b.y; acc[3][2] += a.w * b.z; acc[3][3] += a.w * b.w;
    }
    __syncthreads();
  }

#pragma unroll
  for (int i = 0; i < 4; ++i) {
    int row = bm + ty * 4 + i;
    if (row >= M) continue;
    float4 v;
    if (MODE == 0) {
      float s = sb[row];
      v = make_float4(acc[i][0] * s, acc[i][1] * s, acc[i][2] * s, acc[i][3] * s);
    } else {
      int col = bn + tx * 4;
      v = make_float4(acc[i][0] + sb[col], acc[i][1] + sb[col + 1],
                      acc[i][2] + sb[col + 2], acc[i][3] + sb[col + 3]);
    }
    *reinterpret_cast<float4*>(&C[(size_t)row * N + bn + tx * 4]) = v;
  }
}

// ------------------------- aggregation + bias + dropout + relu -------------------------
template <int F>
__global__ __launch_bounds__(F) void k_agg(const float* __restrict__ hws,
                                           const float* __restrict__ dinv,
                                           const float* __restrict__ bias,
                                           const int* __restrict__ row_start,
                                           const int* __restrict__ csr_src,
                                           float* __restrict__ out,
                                           uint32_t k0, uint32_t k1) {
  int t = blockIdx.x;
  int f = threadIdx.x;
  size_t base = (size_t)t * F;
  float acc = hws[base + f];  // self-loop term (already scaled by dinv[t] as "source")
  int e0 = row_start[t], e1 = row_start[t + 1];
  for (int e = e0; e < e1; ++e) {
    int s = csr_src[e];
    acc += hws[(size_t)s * F + f];
  }
  float val = dinv[t] * acc + bias[f];
  uint32_t j = (uint32_t)(base + f);
  float dv = drop_keep(k0, k1, j) ? (val / 0.8f) : 0.0f;  // dropout (keep-prob 0.8)
  out[base + f] = fmaxf(dv, 0.0f);                        // relu
}

// ------------------------- launch -------------------------
static inline size_t ws_align(size_t x) { return (x + 255) & ~(size_t)255; }

extern "C" void kernel_launch(void* const* d_in, const int* in_sizes, int n_in,
                              void* d_out, int out_size, void* d_ws, size_t ws_size,
                              hipStream_t stream) {
  const float* x  = (const float*)d_in[0];
  const float* W1 = (const float*)d_in[1];
  const float* b1 = (const float*)d_in[2];
  const float* W2 = (const float*)d_in[3];
  const float* b2 = (const float*)d_in[4];
  const float* W3 = (const float*)d_in[5];
  const float* b3 = (const float*)d_in[6];
  const int*   ei = (const int*)d_in[7];

  const int IN = 128, H2 = 256, HID = 128, OD = 64;
  const int n = in_sizes[0] / IN;   // 50000
  const int E = in_sizes[7] / 2;    // 800000
  const int* esrc = ei;
  const int* etgt = ei + E;

  // workspace carve (~107 MB)
  char* w = (char*)d_ws;
  size_t off = 0;
  auto alloc = [&](size_t bytes) { void* p = w + off; off += ws_align(bytes); return p; };
  float* dinv      = (float*)alloc((size_t)n * 4);
  int*   cnt       = (int*)alloc((size_t)n * 4);
  int*   cursor    = (int*)alloc((size_t)n * 4);
  int*   row_start = (int*)alloc(((size_t)n + 1) * 4);
  int*   csr_src   = (int*)alloc((size_t)E * 4);
  float* bufA      = (float*)alloc((size_t)n * H2 * 4);
  float* bufB      = (float*)alloc((size_t)n * H2 * 4);
  (void)ws_size;

  // host-side key derivation: key(42) = (0,42); partitionable "foldlike" split:
  // dk1 = enc(key,(0,0)), dk2 = enc(key,(0,1))  (both output words form the child key)
  uint32_t dk1_0, dk1_1, dk2_0, dk2_1;
  threefry2x32(0u, 42u, 0u, 0u, dk1_0, dk1_1);
  threefry2x32(0u, 42u, 0u, 1u, dk2_0, dk2_1);

  hipMemsetAsync(cnt, 0, (size_t)n * 4, stream);
  hipMemsetAsync(cursor, 0, (size_t)n * 4, stream);
  k_hist<<<(E + 255) / 256, 256, 0, stream>>>(etgt, cnt, E);
  k_scan<<<1, 256, 0, stream>>>(cnt, row_start, dinv, n);
  k_scatter<<<(E + 255) / 256, 256, 0, stream>>>(esrc, etgt, row_start, cursor, csr_src, E);

  dim3 g1((n + 63) / 64, H2 / 64);
  k_gemm<0><<<g1, 256, 0, stream>>>(x, W1, dinv, bufA, n, H2, IN);
  k_agg<256><<<n, 256, 0, stream>>>(bufA, dinv, b1, row_start, csr_src, bufB, dk1_0, dk1_1);

  dim3 g2((n + 63) / 64, HID / 64);
  k_gemm<0><<<g2, 256, 0, stream>>>(bufB, W2, dinv, bufA, n, HID, H2);
  k_agg<128><<<n, 128, 0, stream>>>(bufA, dinv, b2, row_start, csr_src, bufB, dk2_0, dk2_1);

  dim3 g3((n + 63) / 64, OD / 64);
  k_gemm<1><<<g3, 256, 0, stream>>>(bufB, W3, b3, (float*)d_out, n, OD, HID);
}

// Round 2
// 535.556 us; speedup vs baseline: 1.2432x; 1.2432x over previous
//
#include <hip/hip_runtime.h>
#include <stdint.h>

// ---------------------------------------------------------------------------
// GCN 3-layer forward, MI355X. Round 2:
//  - layer 1 restructured as (A_hat x) @ W1  -> gather on 128 feats, not 256
//  - GEMM: 128x64 tile, 8x4 micro, float4 loads (32 FMA : 3 ds_read_b128)
//  - aggregation: one wave per node, float2 per lane
//  - scan parallelized (1024 threads, shfl scan)
// Pipeline:
//   CSR build (hist/scan/scatter)
//   xs   = x * dinv[row]                                  (k_scale)
//   ag   = dinv[t] * (sum xs[src] + xs[t])                (k_agg_w<0>)
//   h1   = relu(drop(ag @ W1 + b1, dk1))                  (k_gemm<2>)
//   hw2  = (h1 @ W2) * dinv[row]                          (k_gemm<0>)
//   h2   = relu(drop(dinv[t]*(sum hw2[src]+hw2[t])+b2,dk2)) (k_agg_w<1>)
//   out  = h2 @ W3 + b3                                   (k_gemm<1>)
// ---------------------------------------------------------------------------

__device__ __host__ __forceinline__ uint32_t tf_rotl(uint32_t v, int r) {
  return (v << r) | (v >> (32 - r));
}

__device__ __host__ __forceinline__ void threefry2x32(uint32_t k0, uint32_t k1,
                                                      uint32_t x0, uint32_t x1,
                                                      uint32_t& o0, uint32_t& o1) {
  const uint32_t k2 = k0 ^ k1 ^ 0x1BD11BDAu;
  x0 += k0; x1 += k1;
#define TFR(r) { x0 += x1; x1 = tf_rotl(x1, r); x1 ^= x0; }
  TFR(13) TFR(15) TFR(26) TFR(6)
  x0 += k1; x1 += k2 + 1u;
  TFR(17) TFR(29) TFR(16) TFR(24)
  x0 += k2; x1 += k0 + 2u;
  TFR(13) TFR(15) TFR(26) TFR(6)
  x0 += k0; x1 += k1 + 3u;
  TFR(17) TFR(29) TFR(16) TFR(24)
  x0 += k1; x1 += k2 + 4u;
  TFR(13) TFR(15) TFR(26) TFR(6)
  x0 += k2; x1 += k0 + 5u;
#undef TFR
  o0 = x0; o1 = x1;
}

__device__ __forceinline__ bool drop_keep(uint32_t k0, uint32_t k1, uint32_t j) {
  uint32_t a, b;
  threefry2x32(k0, k1, 0u, j, a, b);
  uint32_t bits = a ^ b;
  float u = __uint_as_float((bits >> 9) | 0x3f800000u) - 1.0f;
  return u < 0.8f;
}

// ------------------------- CSR build -------------------------
__global__ void k_hist(const int* __restrict__ tgt, int* __restrict__ cnt, int E) {
  int e = blockIdx.x * 256 + threadIdx.x;
  if (e < E) atomicAdd(&cnt[tgt[e]], 1);
}

// single block, 1024 threads: exclusive scan of cnt -> row_start, plus dinv
__global__ __launch_bounds__(1024) void k_scan(const int* __restrict__ cnt,
                                               int* __restrict__ row_start,
                                               float* __restrict__ dinv, int n) {
  const int T = 1024;
  int tid = threadIdx.x;
  int chunk = (n + T - 1) / T;
  int lo = tid * chunk;
  int hi = min(lo + chunk, n);
  int sum = 0;
  for (int i = lo; i < hi; ++i) sum += cnt[i];
  int lane = tid & 63, wv = tid >> 6;
  int v = sum;
#pragma unroll
  for (int d = 1; d < 64; d <<= 1) {
    int u = __shfl_up(v, d);
    if (lane >= d) v += u;
  }
  __shared__ int wsum[16];
  __shared__ int wbase[17];
  if (lane == 63) wsum[wv] = v;
  __syncthreads();
  if (tid == 0) {
    int a = 0;
    for (int i = 0; i < 16; ++i) { wbase[i] = a; a += wsum[i]; }
    wbase[16] = a;
  }
  __syncthreads();
  int run = wbase[wv] + v - sum;  // exclusive prefix of this thread's chunk
  for (int i = lo; i < hi; ++i) {
    row_start[i] = run;
    int c = cnt[i];
    run += c;
    dinv[i] = rsqrtf((float)(c + 1));  // +1 self-loop
  }
  if (tid == T - 1) row_start[n] = wbase[16];
}

__global__ void k_scatter(const int* __restrict__ src, const int* __restrict__ tgt,
                          const int* __restrict__ row_start, int* __restrict__ cursor,
                          int* __restrict__ csr_src, int E) {
  int e = blockIdx.x * 256 + threadIdx.x;
  if (e >= E) return;
  int t = tgt[e];
  int pos = atomicAdd(&cursor[t], 1);
  csr_src[row_start[t] + pos] = src[e];
}

// ------------------------- xs = x * dinv[row] (float4, F=128) -------------------------
__global__ void k_scale(const float* __restrict__ x, const float* __restrict__ dinv,
                        float* __restrict__ xs, int total4) {
  int i = blockIdx.x * 256 + threadIdx.x;
  if (i >= total4) return;
  float4 v = ((const float4*)x)[i];
  float s = dinv[i >> 5];  // 32 float4 per 128-float row
  ((float4*)xs)[i] = make_float4(v.x * s, v.y * s, v.z * s, v.w * s);
}

// ------------------------- GEMM 128x64 tile, 8x4 micro -------------------------
// MODE 0: C = acc * sb[row]                      (dinv row-scale)
// MODE 1: C = acc + sb[col]                      (bias only, final layer)
// MODE 2: C = relu(dropout(acc + sb[col]))       (layer-1 epilogue)
template <int MODE>
__global__ __launch_bounds__(256) void k_gemm(const float* __restrict__ A,
                                              const float* __restrict__ B,
                                              const float* __restrict__ sb,
                                              float* __restrict__ C,
                                              int M, int N, int K,
                                              uint32_t k0, uint32_t k1) {
  const int BM = 128, BN = 64, BK = 16;
  __shared__ float As[BK][BM + 4];
  __shared__ float Bs[BK][BN];
  int tid = threadIdx.x;
  int bm = blockIdx.x * BM, bn = blockIdx.y * BN;

  // loader coords
  int la_k4 = (tid & 3) * 4;   // k offset (float4 over k)
  int la_m  = tid >> 2;        // 0..63, rows in 2 passes of 64
  int lb_k  = tid >> 4;        // 0..15
  int lb_n4 = (tid & 15) * 4;  // col offset (float4 over n)

  // compute coords: 16x16 thread grid, each 8 rows x 4 cols
  int tx = tid & 15, ty = tid >> 4;

  float acc[8][4] = {};

  for (int kk = 0; kk < K; kk += BK) {
#pragma unroll
    for (int i = 0; i < 2; ++i) {
      int row = bm + la_m + i * 64;
      float4 a = (row < M) ? *(const float4*)&A[(size_t)row * K + kk + la_k4]
                           : make_float4(0.f, 0.f, 0.f, 0.f);
      As[la_k4 + 0][la_m + i * 64] = a.x;
      As[la_k4 + 1][la_m + i * 64] = a.y;
      As[la_k4 + 2][la_m + i * 64] = a.z;
      As[la_k4 + 3][la_m + i * 64] = a.w;
    }
    *(float4*)&Bs[lb_k][lb_n4] = *(const float4*)&B[(size_t)(kk + lb_k) * N + bn + lb_n4];
    __syncthreads();
#pragma unroll
    for (int k = 0; k < BK; ++k) {
      float4 a0 = *(const float4*)&As[k][ty * 8];
      float4 a1 = *(const float4*)&As[k][ty * 8 + 4];
      float4 b  = *(const float4*)&Bs[k][tx * 4];
      float av[8] = {a0.x, a0.y, a0.z, a0.w, a1.x, a1.y, a1.z, a1.w};
      float bv[4] = {b.x, b.y, b.z, b.w};
#pragma unroll
      for (int i = 0; i < 8; ++i)
#pragma unroll
        for (int j = 0; j < 4; ++j) acc[i][j] += av[i] * bv[j];
    }
    __syncthreads();
  }

#pragma unroll
  for (int i = 0; i < 8; ++i) {
    int row = bm + ty * 8 + i;
    if (row >= M) continue;
    int col = bn + tx * 4;
    float4 v;
    if (MODE == 0) {
      float s = sb[row];
      v = make_float4(acc[i][0] * s, acc[i][1] * s, acc[i][2] * s, acc[i][3] * s);
    } else {
      v = make_float4(acc[i][0] + sb[col], acc[i][1] + sb[col + 1],
                      acc[i][2] + sb[col + 2], acc[i][3] + sb[col + 3]);
      if (MODE == 2) {
        uint32_t j0 = (uint32_t)row * (uint32_t)N + (uint32_t)col;
        v.x = drop_keep(k0, k1, j0 + 0) ? fmaxf(v.x * 1.25f, 0.f) : 0.f;
        v.y = drop_keep(k0, k1, j0 + 1) ? fmaxf(v.y * 1.25f, 0.f) : 0.f;
        v.z = drop_keep(k0, k1, j0 + 2) ? fmaxf(v.z * 1.25f, 0.f) : 0.f;
        v.w = drop_keep(k0, k1, j0 + 3) ? fmaxf(v.w * 1.25f, 0.f) : 0.f;
      }
    }
    *reinterpret_cast<float4*>(&C[(size_t)row * N + col]) = v;
  }
}

// ------------------------- aggregation: one wave per node, float2/lane, F=128 ----
// MODE 0: out[t] = dinv[t] * (sum xs[src] + xs[t])
// MODE 1: out[t] = relu(dropout(dinv[t]*(sum hw[src]+hw[t]) + bias, key))
template <int MODE>
__global__ __launch_bounds__(256) void k_agg_w(const float* __restrict__ hws,
                                               const float* __restrict__ dinv,
                                               const float* __restrict__ bias,
                                               const int* __restrict__ row_start,
                                               const int* __restrict__ csr_src,
                                               float* __restrict__ out,
                                               uint32_t k0, uint32_t k1, int n) {
  const int F = 128;
  int wid = (int)((blockIdx.x * 256 + threadIdx.x) >> 6);  // one wave per node
  if (wid >= n) return;
  int lane = threadIdx.x & 63;
  int t = wid;
  const float2* selfrow = (const float2*)(hws + (size_t)t * F);
  float2 acc = selfrow[lane];
  int e0 = row_start[t], e1 = row_start[t + 1];
  for (int e = e0; e < e1; ++e) {
    int s = csr_src[e];  // wave-uniform broadcast load
    float2 v = ((const float2*)(hws + (size_t)s * F))[lane];
    acc.x += v.x;
    acc.y += v.y;
  }
  float d = dinv[t];
  size_t base = (size_t)t * F + lane * 2;
  if (MODE == 0) {
    ((float2*)out)[base >> 1] = make_float2(acc.x * d, acc.y * d);
  } else {
    float vx = acc.x * d + bias[lane * 2];
    float vy = acc.y * d + bias[lane * 2 + 1];
    uint32_t j = (uint32_t)base;
    vx = drop_keep(k0, k1, j)     ? fmaxf(vx * 1.25f, 0.f) : 0.f;
    vy = drop_keep(k0, k1, j + 1) ? fmaxf(vy * 1.25f, 0.f) : 0.f;
    ((float2*)out)[base >> 1] = make_float2(vx, vy);
  }
}

// ------------------------- launch -------------------------
static inline size_t ws_align(size_t x) { return (x + 255) & ~(size_t)255; }

extern "C" void kernel_launch(void* const* d_in, const int* in_sizes, int n_in,
                              void* d_out, int out_size, void* d_ws, size_t ws_size,
                              hipStream_t stream) {
  const float* x  = (const float*)d_in[0];
  const float* W1 = (const float*)d_in[1];
  const float* b1 = (const float*)d_in[2];
  const float* W2 = (const float*)d_in[3];
  const float* b2 = (const float*)d_in[4];
  const float* W3 = (const float*)d_in[5];
  const float* b3 = (const float*)d_in[6];
  const int*   ei = (const int*)d_in[7];

  const int IN = 128, H2 = 256, HID = 128, OD = 64;
  const int n = in_sizes[0] / IN;   // 50000
  const int E = in_sizes[7] / 2;    // 800000
  const int* esrc = ei;
  const int* etgt = ei + E;

  char* w = (char*)d_ws;
  size_t off = 0;
  auto alloc = [&](size_t bytes) { void* p = w + off; off += ws_align(bytes); return p; };
  float* dinv      = (float*)alloc((size_t)n * 4);
  int*   cnt       = (int*)alloc((size_t)n * 4);
  int*   cursor    = (int*)alloc((size_t)n * 4);
  int*   row_start = (int*)alloc(((size_t)n + 1) * 4);
  int*   csr_src   = (int*)alloc((size_t)E * 4);
  float* bufS      = (float*)alloc((size_t)n * IN * 4);   // xs, later hw2
  float* bufG      = (float*)alloc((size_t)n * IN * 4);   // agg1 out, later h2
  float* bufH1     = (float*)alloc((size_t)n * H2 * 4);   // h1
  (void)ws_size;

  // dropout child keys (partitionable threefry fold-like split of key(42))
  uint32_t dk1_0, dk1_1, dk2_0, dk2_1;
  threefry2x32(0u, 42u, 0u, 0u, dk1_0, dk1_1);
  threefry2x32(0u, 42u, 0u, 1u, dk2_0, dk2_1);

  hipMemsetAsync(cnt, 0, (size_t)n * 4, stream);
  hipMemsetAsync(cursor, 0, (size_t)n * 4, stream);
  k_hist<<<(E + 255) / 256, 256, 0, stream>>>(etgt, cnt, E);
  k_scan<<<1, 1024, 0, stream>>>(cnt, row_start, dinv, n);
  k_scatter<<<(E + 255) / 256, 256, 0, stream>>>(esrc, etgt, row_start, cursor, csr_src, E);

  // layer 1: aggregate-first
  int total4 = n * IN / 4;
  k_scale<<<(total4 + 255) / 256, 256, 0, stream>>>(x, dinv, bufS, total4);
  k_agg_w<0><<<(n + 3) / 4, 256, 0, stream>>>(bufS, dinv, nullptr, row_start, csr_src,
                                              bufG, 0u, 0u, n);
  dim3 g1((n + 127) / 128, H2 / 64);
  k_gemm<2><<<g1, 256, 0, stream>>>(bufG, W1, b1, bufH1, n, H2, IN, dk1_0, dk1_1);

  // layer 2: transform-first
  dim3 g2((n + 127) / 128, HID / 64);
  k_gemm<0><<<g2, 256, 0, stream>>>(bufH1, W2, dinv, bufS, n, HID, H2, 0u, 0u);
  k_agg_w<1><<<(n + 3) / 4, 256, 0, stream>>>(bufS, dinv, b2, row_start, csr_src,
                                              bufG, dk2_0, dk2_1, n);

  // layer 3
  dim3 g3((n + 127) / 128, OD / 64);
  k_gemm<1><<<g3, 256, 0, stream>>>(bufG, W3, b3, (float*)d_out, n, OD, HID, 0u, 0u);
}

// Round 3
// 425.444 us; speedup vs baseline: 1.5650x; 1.2588x over previous
//
#include <hip/hip_runtime.h>
#include <stdint.h>

// ---------------------------------------------------------------------------
// GCN 3-layer forward, MI355X. Round 3:
//  - hierarchical scan (196 blocks + block-sum scan + offset add): was 107us single-block
//  - GEMM 128x128 tile, 8x8 micro with split row/col groups (2-way LDS aliasing = free)
//  - k_scale fused into layer-1 aggregation (gather x with per-src dinv)
// Pipeline:
//   CSR build (hist / scan1+scan2+scan3 / scatter)
//   ag   = dinv[t] * (sum_{s} x[s]*dinv[s] + x[t]*dinv[t])    (k_agg_x)
//   h1   = relu(drop(ag @ W1 + b1, dk1))                      (k_gemm2<2>)
//   hw2  = (h1 @ W2) * dinv[row]                              (k_gemm2<0>)
//   h2   = relu(drop(dinv[t]*(sum hw2[src]+hw2[t])+b2,dk2))   (k_agg_w<1>)
//   out  = h2 @ W3 + b3                                       (k_gemm<1>, 128x64)
// ---------------------------------------------------------------------------

__device__ __host__ __forceinline__ uint32_t tf_rotl(uint32_t v, int r) {
  return (v << r) | (v >> (32 - r));
}

__device__ __host__ __forceinline__ void threefry2x32(uint32_t k0, uint32_t k1,
                                                      uint32_t x0, uint32_t x1,
                                                      uint32_t& o0, uint32_t& o1) {
  const uint32_t k2 = k0 ^ k1 ^ 0x1BD11BDAu;
  x0 += k0; x1 += k1;
#define TFR(r) { x0 += x1; x1 = tf_rotl(x1, r); x1 ^= x0; }
  TFR(13) TFR(15) TFR(26) TFR(6)
  x0 += k1; x1 += k2 + 1u;
  TFR(17) TFR(29) TFR(16) TFR(24)
  x0 += k2; x1 += k0 + 2u;
  TFR(13) TFR(15) TFR(26) TFR(6)
  x0 += k0; x1 += k1 + 3u;
  TFR(17) TFR(29) TFR(16) TFR(24)
  x0 += k1; x1 += k2 + 4u;
  TFR(13) TFR(15) TFR(26) TFR(6)
  x0 += k2; x1 += k0 + 5u;
#undef TFR
  o0 = x0; o1 = x1;
}

__device__ __forceinline__ bool drop_keep(uint32_t k0, uint32_t k1, uint32_t j) {
  uint32_t a, b;
  threefry2x32(k0, k1, 0u, j, a, b);
  uint32_t bits = a ^ b;
  float u = __uint_as_float((bits >> 9) | 0x3f800000u) - 1.0f;
  return u < 0.8f;
}

// ------------------------- CSR build -------------------------
__global__ void k_hist(const int* __restrict__ tgt, int* __restrict__ cnt, int E) {
  int e = blockIdx.x * 256 + threadIdx.x;
  if (e < E) atomicAdd(&cnt[tgt[e]], 1);
}

// phase 1: per-block inclusive scan; write block-local exclusive into row_start,
// block total into bsum; also dinv.
__global__ __launch_bounds__(256) void k_scan1(const int* __restrict__ cnt,
                                               int* __restrict__ row_start,
                                               int* __restrict__ bsum,
                                               float* __restrict__ dinv, int n) {
  int tid = threadIdx.x;
  int i = blockIdx.x * 256 + tid;
  int c = (i < n) ? cnt[i] : 0;
  if (i < n) dinv[i] = rsqrtf((float)(c + 1));  // +1 self-loop
  int lane = tid & 63, wv = tid >> 6;
  int v = c;
#pragma unroll
  for (int d = 1; d < 64; d <<= 1) {
    int u = __shfl_up(v, d);
    if (lane >= d) v += u;
  }
  __shared__ int ws[4];
  if (lane == 63) ws[wv] = v;
  __syncthreads();
  int add = 0;
#pragma unroll
  for (int w = 0; w < 4; ++w)
    if (w < wv) add += ws[w];
  int incl = v + add;
  if (i < n) row_start[i] = incl - c;
  if (tid == 255) bsum[blockIdx.x] = incl;
}

// phase 2: single block scans block sums (nb <= 256) -> exclusive bbase; total -> row_start[n]
__global__ __launch_bounds__(256) void k_scan2(const int* __restrict__ bsum,
                                               int* __restrict__ bbase,
                                               int* __restrict__ row_start,
                                               int nb, int n) {
  int tid = threadIdx.x;
  int c = (tid < nb) ? bsum[tid] : 0;
  int lane = tid & 63, wv = tid >> 6;
  int v = c;
#pragma unroll
  for (int d = 1; d < 64; d <<= 1) {
    int u = __shfl_up(v, d);
    if (lane >= d) v += u;
  }
  __shared__ int ws[4];
  if (lane == 63) ws[wv] = v;
  __syncthreads();
  int add = 0;
#pragma unroll
  for (int w = 0; w < 4; ++w)
    if (w < wv) add += ws[w];
  int incl = v + add;
  if (tid < nb) bbase[tid] = incl - c;
  if (tid == 255) row_start[n] = incl;
}

// phase 3: add block offsets in place
__global__ void k_scan3(int* __restrict__ row_start, const int* __restrict__ bbase, int n) {
  int i = blockIdx.x * 256 + threadIdx.x;
  if (i < n) row_start[i] += bbase[blockIdx.x];
}

__global__ void k_scatter(const int* __restrict__ src, const int* __restrict__ tgt,
                          const int* __restrict__ row_start, int* __restrict__ cursor,
                          int* __restrict__ csr_src, int E) {
  int e = blockIdx.x * 256 + threadIdx.x;
  if (e >= E) return;
  int t = tgt[e];
  int pos = atomicAdd(&cursor[t], 1);
  csr_src[row_start[t] + pos] = src[e];
}

// ------------------------- GEMM 128x128 tile, 8x8 micro (split groups) ----------
// thread (tx,ty), tx=tid&15, ty=tid>>4: rows {ty*4+i, ty*4+64+i}, cols {tx*4+j, tx*4+64+j}
// MODE 0: C = acc * sb[row];  MODE 2: C = relu(dropout(acc + sb[col]))
template <int MODE>
__global__ __launch_bounds__(256) void k_gemm2(const float* __restrict__ A,
                                               const float* __restrict__ B,
                                               const float* __restrict__ sb,
                                               float* __restrict__ C,
                                               int M, int N, int K,
                                               uint32_t k0, uint32_t k1) {
  const int BM = 128, BN = 128, BK = 16;
  __shared__ float As[BK][BM + 4];
  __shared__ float Bs[BK][BN];
  int tid = threadIdx.x;
  int bm = blockIdx.x * BM, bn = blockIdx.y * BN;

  int la_k4 = (tid & 3) * 4;   // k offset, float4 over k
  int la_m  = tid >> 2;        // 0..63 (+64 second pass)
  int lb_k  = tid >> 5;        // 0..7 (+8 second pass)
  int lb_n4 = (tid & 31) * 4;  // 0..124

  int tx = tid & 15, ty = tid >> 4;

  float acc[2][4][2][4] = {};  // [rowgrp][i][colgrp][j]

  for (int kk = 0; kk < K; kk += BK) {
#pragma unroll
    for (int i = 0; i < 2; ++i) {
      int row = bm + la_m + i * 64;
      float4 a = (row < M) ? *(const float4*)&A[(size_t)row * K + kk + la_k4]
                           : make_float4(0.f, 0.f, 0.f, 0.f);
      As[la_k4 + 0][la_m + i * 64] = a.x;
      As[la_k4 + 1][la_m + i * 64] = a.y;
      As[la_k4 + 2][la_m + i * 64] = a.z;
      As[la_k4 + 3][la_m + i * 64] = a.w;
    }
#pragma unroll
    for (int i = 0; i < 2; ++i) {
      *(float4*)&Bs[lb_k + i * 8][lb_n4] =
          *(const float4*)&B[(size_t)(kk + lb_k + i * 8) * N + bn + lb_n4];
    }
    __syncthreads();
#pragma unroll
    for (int k = 0; k < BK; ++k) {
      float4 a0 = *(const float4*)&As[k][ty * 4];
      float4 a1 = *(const float4*)&As[k][ty * 4 + 64];
      float4 b0 = *(const float4*)&Bs[k][tx * 4];
      float4 b1 = *(const float4*)&Bs[k][tx * 4 + 64];
      float av[2][4] = {{a0.x, a0.y, a0.z, a0.w}, {a1.x, a1.y, a1.z, a1.w}};
      float bv[2][4] = {{b0.x, b0.y, b0.z, b0.w}, {b1.x, b1.y, b1.z, b1.w}};
#pragma unroll
      for (int rg = 0; rg < 2; ++rg)
#pragma unroll
        for (int i = 0; i < 4; ++i)
#pragma unroll
          for (int cg = 0; cg < 2; ++cg)
#pragma unroll
            for (int j = 0; j < 4; ++j) acc[rg][i][cg][j] += av[rg][i] * bv[cg][j];
    }
    __syncthreads();
  }

#pragma unroll
  for (int rg = 0; rg < 2; ++rg) {
#pragma unroll
    for (int i = 0; i < 4; ++i) {
      int row = bm + ty * 4 + rg * 64 + i;
      if (row >= M) continue;
#pragma unroll
      for (int cg = 0; cg < 2; ++cg) {
        int col = bn + tx * 4 + cg * 64;
        float4 v;
        if (MODE == 0) {
          float s = sb[row];
          v = make_float4(acc[rg][i][cg][0] * s, acc[rg][i][cg][1] * s,
                          acc[rg][i][cg][2] * s, acc[rg][i][cg][3] * s);
        } else {
          v = make_float4(acc[rg][i][cg][0] + sb[col], acc[rg][i][cg][1] + sb[col + 1],
                          acc[rg][i][cg][2] + sb[col + 2], acc[rg][i][cg][3] + sb[col + 3]);
          uint32_t j0 = (uint32_t)row * (uint32_t)N + (uint32_t)col;
          v.x = drop_keep(k0, k1, j0 + 0) ? fmaxf(v.x * 1.25f, 0.f) : 0.f;
          v.y = drop_keep(k0, k1, j0 + 1) ? fmaxf(v.y * 1.25f, 0.f) : 0.f;
          v.z = drop_keep(k0, k1, j0 + 2) ? fmaxf(v.z * 1.25f, 0.f) : 0.f;
          v.w = drop_keep(k0, k1, j0 + 3) ? fmaxf(v.w * 1.25f, 0.f) : 0.f;
        }
        *reinterpret_cast<float4*>(&C[(size_t)row * N + col]) = v;
      }
    }
  }
}

// ------------------------- GEMM 128x64 (final layer, N=64) -------------------------
__global__ __launch_bounds__(256) void k_gemm_f(const float* __restrict__ A,
                                                const float* __restrict__ B,
                                                const float* __restrict__ sb,
                                                float* __restrict__ C,
                                                int M, int N, int K) {
  const int BM = 128, BK = 16;
  __shared__ float As[BK][BM + 4];
  __shared__ float Bs[BK][64];
  int tid = threadIdx.x;
  int bm = blockIdx.x * BM;

  int la_k4 = (tid & 3) * 4;
  int la_m  = tid >> 2;
  int lb_k  = tid >> 4;        // 0..15
  int lb_n4 = (tid & 15) * 4;  // 0..60
  int tx = tid & 15, ty = tid >> 4;

  float acc[8][4] = {};

  for (int kk = 0; kk < K; kk += BK) {
#pragma unroll
    for (int i = 0; i < 2; ++i) {
      int row = bm + la_m + i * 64;
      float4 a = (row < M) ? *(const float4*)&A[(size_t)row * K + kk + la_k4]
                           : make_float4(0.f, 0.f, 0.f, 0.f);
      As[la_k4 + 0][la_m + i * 64] = a.x;
      As[la_k4 + 1][la_m + i * 64] = a.y;
      As[la_k4 + 2][la_m + i * 64] = a.z;
      As[la_k4 + 3][la_m + i * 64] = a.w;
    }
    *(float4*)&Bs[lb_k][lb_n4] = *(const float4*)&B[(size_t)(kk + lb_k) * N + lb_n4];
    __syncthreads();
#pragma unroll
    for (int k = 0; k < BK; ++k) {
      float4 a0 = *(const float4*)&As[k][ty * 8];
      float4 a1 = *(const float4*)&As[k][ty * 8 + 4];
      float4 b  = *(const float4*)&Bs[k][tx * 4];
      float av[8] = {a0.x, a0.y, a0.z, a0.w, a1.x, a1.y, a1.z, a1.w};
      float bv[4] = {b.x, b.y, b.z, b.w};
#pragma unroll
      for (int i = 0; i < 8; ++i)
#pragma unroll
        for (int j = 0; j < 4; ++j) acc[i][j] += av[i] * bv[j];
    }
    __syncthreads();
  }

#pragma unroll
  for (int i = 0; i < 8; ++i) {
    int row = bm + ty * 8 + i;
    if (row >= M) continue;
    int col = tx * 4;
    float4 v = make_float4(acc[i][0] + sb[col], acc[i][1] + sb[col + 1],
                           acc[i][2] + sb[col + 2], acc[i][3] + sb[col + 3]);
    *reinterpret_cast<float4*>(&C[(size_t)row * N + col]) = v;
  }
}

// ------------------------- layer-1 aggregation (gathers x directly) ----------------
// out[t] = dinv[t] * ( x[t]*dinv[t] + sum_{s} x[s]*dinv[s] )
__global__ __launch_bounds__(256) void k_agg_x(const float* __restrict__ x,
                                               const float* __restrict__ dinv,
                                               const int* __restrict__ row_start,
                                               const int* __restrict__ csr_src,
                                               float* __restrict__ out, int n) {
  const int F = 128;
  int wid = (int)((blockIdx.x * 256 + threadIdx.x) >> 6);
  if (wid >= n) return;
  int lane = threadIdx.x & 63;
  int t = wid;
  float dt = dinv[t];
  float2 xt = ((const float2*)(x + (size_t)t * F))[lane];
  float2 acc = make_float2(xt.x * dt, xt.y * dt);
  int e0 = row_start[t], e1 = row_start[t + 1];
  for (int e = e0; e < e1; ++e) {
    int s = csr_src[e];
    float ds = dinv[s];
    float2 v = ((const float2*)(x + (size_t)s * F))[lane];
    acc.x += v.x * ds;
    acc.y += v.y * ds;
  }
  ((float2*)out)[(size_t)t * (F / 2) + lane] = make_float2(acc.x * dt, acc.y * dt);
}

// ------------------------- layer-2 aggregation + bias + dropout + relu ------------
__global__ __launch_bounds__(256) void k_agg_w(const float* __restrict__ hws,
                                               const float* __restrict__ dinv,
                                               const float* __restrict__ bias,
                                               const int* __restrict__ row_start,
                                               const int* __restrict__ csr_src,
                                               float* __restrict__ out,
                                               uint32_t k0, uint32_t k1, int n) {
  const int F = 128;
  int wid = (int)((blockIdx.x * 256 + threadIdx.x) >> 6);
  if (wid >= n) return;
  int lane = threadIdx.x & 63;
  int t = wid;
  float2 acc = ((const float2*)(hws + (size_t)t * F))[lane];
  int e0 = row_start[t], e1 = row_start[t + 1];
  for (int e = e0; e < e1; ++e) {
    int s = csr_src[e];
    float2 v = ((const float2*)(hws + (size_t)s * F))[lane];
    acc.x += v.x;
    acc.y += v.y;
  }
  float d = dinv[t];
  size_t base = (size_t)t * F + lane * 2;
  float vx = acc.x * d + bias[lane * 2];
  float vy = acc.y * d + bias[lane * 2 + 1];
  uint32_t j = (uint32_t)base;
  vx = drop_keep(k0, k1, j)     ? fmaxf(vx * 1.25f, 0.f) : 0.f;
  vy = drop_keep(k0, k1, j + 1) ? fmaxf(vy * 1.25f, 0.f) : 0.f;
  ((float2*)out)[base >> 1] = make_float2(vx, vy);
}

// ------------------------- launch -------------------------
static inline size_t ws_align(size_t x) { return (x + 255) & ~(size_t)255; }

extern "C" void kernel_launch(void* const* d_in, const int* in_sizes, int n_in,
                              void* d_out, int out_size, void* d_ws, size_t ws_size,
                              hipStream_t stream) {
  const float* x  = (const float*)d_in[0];
  const float* W1 = (const float*)d_in[1];
  const float* b1 = (const float*)d_in[2];
  const float* W2 = (const float*)d_in[3];
  const float* b2 = (const float*)d_in[4];
  const float* W3 = (const float*)d_in[5];
  const float* b3 = (const float*)d_in[6];
  const int*   ei = (const int*)d_in[7];

  const int IN = 128, H2 = 256, HID = 128, OD = 64;
  const int n = in_sizes[0] / IN;   // 50000
  const int E = in_sizes[7] / 2;    // 800000
  const int* esrc = ei;
  const int* etgt = ei + E;
  const int nb = (n + 255) / 256;   // 196 scan blocks

  char* w = (char*)d_ws;
  size_t off = 0;
  auto alloc = [&](size_t bytes) { void* p = w + off; off += ws_align(bytes); return p; };
  float* dinv      = (float*)alloc((size_t)n * 4);
  int*   cnt       = (int*)alloc((size_t)n * 4);
  int*   cursor    = (int*)alloc((size_t)n * 4);
  int*   row_start = (int*)alloc(((size_t)n + 1) * 4);
  int*   bsum      = (int*)alloc(256 * 4);
  int*   bbase     = (int*)alloc(256 * 4);
  int*   csr_src   = (int*)alloc((size_t)E * 4);
  float* bufS      = (float*)alloc((size_t)n * IN * 4);   // ag, later hw2
  float* bufG      = (float*)alloc((size_t)n * IN * 4);   // h2
  float* bufH1     = (float*)alloc((size_t)n * H2 * 4);   // h1
  (void)ws_size;

  uint32_t dk1_0, dk1_1, dk2_0, dk2_1;
  threefry2x32(0u, 42u, 0u, 0u, dk1_0, dk1_1);
  threefry2x32(0u, 42u, 0u, 1u, dk2_0, dk2_1);

  hipMemsetAsync(cnt, 0, (size_t)n * 4, stream);
  hipMemsetAsync(cursor, 0, (size_t)n * 4, stream);
  k_hist<<<(E + 255) / 256, 256, 0, stream>>>(etgt, cnt, E);
  k_scan1<<<nb, 256, 0, stream>>>(cnt, row_start, bsum, dinv, n);
  k_scan2<<<1, 256, 0, stream>>>(bsum, bbase, row_start, nb, n);
  k_scan3<<<nb, 256, 0, stream>>>(row_start, bbase, n);
  k_scatter<<<(E + 255) / 256, 256, 0, stream>>>(esrc, etgt, row_start, cursor, csr_src, E);

  // layer 1: aggregate-first (gathers x directly, dinv fused)
  k_agg_x<<<(n + 3) / 4, 256, 0, stream>>>(x, dinv, row_start, csr_src, bufS, n);
  dim3 g1((n + 127) / 128, H2 / 128);
  k_gemm2<2><<<g1, 256, 0, stream>>>(bufS, W1, b1, bufH1, n, H2, IN, dk1_0, dk1_1);

  // layer 2: transform-first
  dim3 g2((n + 127) / 128, HID / 128);
  k_gemm2<0><<<g2, 256, 0, stream>>>(bufH1, W2, dinv, bufS, n, HID, H2, 0u, 0u);
  k_agg_w<<<(n + 3) / 4, 256, 0, stream>>>(bufS, dinv, b2, row_start, csr_src,
                                           bufG, dk2_0, dk2_1, n);

  // layer 3
  k_gemm_f<<<(n + 127) / 128, 256, 0, stream>>>(bufG, W3, b3, (float*)d_out, n, OD, HID);
}

// Round 4
// 369.915 us; speedup vs baseline: 1.7999x; 1.1501x over previous
//
#include <hip/hip_runtime.h>
#include <stdint.h>

// ---------------------------------------------------------------------------
// GCN 3-layer forward, MI355X. Round 4:
//  - agg kernels: 4-way MLP unroll (4 independent accumulators, 4 gathers in
//    flight per wave) — round-3 profile showed VALUBusy 12% / 2.3 TB/s =
//    latency-bound serial gather chain.
// Pipeline:
//   CSR build (hist / scan1+scan2+scan3 / scatter)
//   ag   = dinv[t] * (sum_{s} x[s]*dinv[s] + x[t]*dinv[t])    (k_agg_x)
//   h1   = relu(drop(ag @ W1 + b1, dk1))                      (k_gemm2<2>)
//   hw2  = (h1 @ W2) * dinv[row]                              (k_gemm2<0>)
//   h2   = relu(drop(dinv[t]*(sum hw2[src]+hw2[t])+b2,dk2))   (k_agg_w)
//   out  = h2 @ W3 + b3                                       (k_gemm_f)
// ---------------------------------------------------------------------------

__device__ __host__ __forceinline__ uint32_t tf_rotl(uint32_t v, int r) {
  return (v << r) | (v >> (32 - r));
}

__device__ __host__ __forceinline__ void threefry2x32(uint32_t k0, uint32_t k1,
                                                      uint32_t x0, uint32_t x1,
                                                      uint32_t& o0, uint32_t& o1) {
  const uint32_t k2 = k0 ^ k1 ^ 0x1BD11BDAu;
  x0 += k0; x1 += k1;
#define TFR(r) { x0 += x1; x1 = tf_rotl(x1, r); x1 ^= x0; }
  TFR(13) TFR(15) TFR(26) TFR(6)
  x0 += k1; x1 += k2 + 1u;
  TFR(17) TFR(29) TFR(16) TFR(24)
  x0 += k2; x1 += k0 + 2u;
  TFR(13) TFR(15) TFR(26) TFR(6)
  x0 += k0; x1 += k1 + 3u;
  TFR(17) TFR(29) TFR(16) TFR(24)
  x0 += k1; x1 += k2 + 4u;
  TFR(13) TFR(15) TFR(26) TFR(6)
  x0 += k2; x1 += k0 + 5u;
#undef TFR
  o0 = x0; o1 = x1;
}

__device__ __forceinline__ bool drop_keep(uint32_t k0, uint32_t k1, uint32_t j) {
  uint32_t a, b;
  threefry2x32(k0, k1, 0u, j, a, b);
  uint32_t bits = a ^ b;
  float u = __uint_as_float((bits >> 9) | 0x3f800000u) - 1.0f;
  return u < 0.8f;
}

// ------------------------- CSR build -------------------------
__global__ void k_hist(const int* __restrict__ tgt, int* __restrict__ cnt, int E) {
  int e = blockIdx.x * 256 + threadIdx.x;
  if (e < E) atomicAdd(&cnt[tgt[e]], 1);
}

__global__ __launch_bounds__(256) void k_scan1(const int* __restrict__ cnt,
                                               int* __restrict__ row_start,
                                               int* __restrict__ bsum,
                                               float* __restrict__ dinv, int n) {
  int tid = threadIdx.x;
  int i = blockIdx.x * 256 + tid;
  int c = (i < n) ? cnt[i] : 0;
  if (i < n) dinv[i] = rsqrtf((float)(c + 1));  // +1 self-loop
  int lane = tid & 63, wv = tid >> 6;
  int v = c;
#pragma unroll
  for (int d = 1; d < 64; d <<= 1) {
    int u = __shfl_up(v, d);
    if (lane >= d) v += u;
  }
  __shared__ int ws[4];
  if (lane == 63) ws[wv] = v;
  __syncthreads();
  int add = 0;
#pragma unroll
  for (int w = 0; w < 4; ++w)
    if (w < wv) add += ws[w];
  int incl = v + add;
  if (i < n) row_start[i] = incl - c;
  if (tid == 255) bsum[blockIdx.x] = incl;
}

__global__ __launch_bounds__(256) void k_scan2(const int* __restrict__ bsum,
                                               int* __restrict__ bbase,
                                               int* __restrict__ row_start,
                                               int nb, int n) {
  int tid = threadIdx.x;
  int c = (tid < nb) ? bsum[tid] : 0;
  int lane = tid & 63, wv = tid >> 6;
  int v = c;
#pragma unroll
  for (int d = 1; d < 64; d <<= 1) {
    int u = __shfl_up(v, d);
    if (lane >= d) v += u;
  }
  __shared__ int ws[4];
  if (lane == 63) ws[wv] = v;
  __syncthreads();
  int add = 0;
#pragma unroll
  for (int w = 0; w < 4; ++w)
    if (w < wv) add += ws[w];
  int incl = v + add;
  if (tid < nb) bbase[tid] = incl - c;
  if (tid == 255) row_start[n] = incl;
}

__global__ void k_scan3(int* __restrict__ row_start, const int* __restrict__ bbase, int n) {
  int i = blockIdx.x * 256 + threadIdx.x;
  if (i < n) row_start[i] += bbase[blockIdx.x];
}

__global__ void k_scatter(const int* __restrict__ src, const int* __restrict__ tgt,
                          const int* __restrict__ row_start, int* __restrict__ cursor,
                          int* __restrict__ csr_src, int E) {
  int e = blockIdx.x * 256 + threadIdx.x;
  if (e >= E) return;
  int t = tgt[e];
  int pos = atomicAdd(&cursor[t], 1);
  csr_src[row_start[t] + pos] = src[e];
}

// ------------------------- GEMM 128x128 tile, 8x8 micro (split groups) ----------
template <int MODE>
__global__ __launch_bounds__(256) void k_gemm2(const float* __restrict__ A,
                                               const float* __restrict__ B,
                                               const float* __restrict__ sb,
                                               float* __restrict__ C,
                                               int M, int N, int K,
                                               uint32_t k0, uint32_t k1) {
  const int BM = 128, BN = 128, BK = 16;
  __shared__ float As[BK][BM + 4];
  __shared__ float Bs[BK][BN];
  int tid = threadIdx.x;
  int bm = blockIdx.x * BM, bn = blockIdx.y * BN;

  int la_k4 = (tid & 3) * 4;
  int la_m  = tid >> 2;
  int lb_k  = tid >> 5;
  int lb_n4 = (tid & 31) * 4;

  int tx = tid & 15, ty = tid >> 4;

  float acc[2][4][2][4] = {};

  for (int kk = 0; kk < K; kk += BK) {
#pragma unroll
    for (int i = 0; i < 2; ++i) {
      int row = bm + la_m + i * 64;
      float4 a = (row < M) ? *(const float4*)&A[(size_t)row * K + kk + la_k4]
                           : make_float4(0.f, 0.f, 0.f, 0.f);
      As[la_k4 + 0][la_m + i * 64] = a.x;
      As[la_k4 + 1][la_m + i * 64] = a.y;
      As[la_k4 + 2][la_m + i * 64] = a.z;
      As[la_k4 + 3][la_m + i * 64] = a.w;
    }
#pragma unroll
    for (int i = 0; i < 2; ++i) {
      *(float4*)&Bs[lb_k + i * 8][lb_n4] =
          *(const float4*)&B[(size_t)(kk + lb_k + i * 8) * N + bn + lb_n4];
    }
    __syncthreads();
#pragma unroll
    for (int k = 0; k < BK; ++k) {
      float4 a0 = *(const float4*)&As[k][ty * 4];
      float4 a1 = *(const float4*)&As[k][ty * 4 + 64];
      float4 b0 = *(const float4*)&Bs[k][tx * 4];
      float4 b1 = *(const float4*)&Bs[k][tx * 4 + 64];
      float av[2][4] = {{a0.x, a0.y, a0.z, a0.w}, {a1.x, a1.y, a1.z, a1.w}};
      float bv[2][4] = {{b0.x, b0.y, b0.z, b0.w}, {b1.x, b1.y, b1.z, b1.w}};
#pragma unroll
      for (int rg = 0; rg < 2; ++rg)
#pragma unroll
        for (int i = 0; i < 4; ++i)
#pragma unroll
          for (int cg = 0; cg < 2; ++cg)
#pragma unroll
            for (int j = 0; j < 4; ++j) acc[rg][i][cg][j] += av[rg][i] * bv[cg][j];
    }
    __syncthreads();
  }

#pragma unroll
  for (int rg = 0; rg < 2; ++rg) {
#pragma unroll
    for (int i = 0; i < 4; ++i) {
      int row = bm + ty * 4 + rg * 64 + i;
      if (row >= M) continue;
#pragma unroll
      for (int cg = 0; cg < 2; ++cg) {
        int col = bn + tx * 4 + cg * 64;
        float4 v;
        if (MODE == 0) {
          float s = sb[row];
          v = make_float4(acc[rg][i][cg][0] * s, acc[rg][i][cg][1] * s,
                          acc[rg][i][cg][2] * s, acc[rg][i][cg][3] * s);
        } else {
          v = make_float4(acc[rg][i][cg][0] + sb[col], acc[rg][i][cg][1] + sb[col + 1],
                          acc[rg][i][cg][2] + sb[col + 2], acc[rg][i][cg][3] + sb[col + 3]);
          uint32_t j0 = (uint32_t)row * (uint32_t)N + (uint32_t)col;
          v.x = drop_keep(k0, k1, j0 + 0) ? fmaxf(v.x * 1.25f, 0.f) : 0.f;
          v.y = drop_keep(k0, k1, j0 + 1) ? fmaxf(v.y * 1.25f, 0.f) : 0.f;
          v.z = drop_keep(k0, k1, j0 + 2) ? fmaxf(v.z * 1.25f, 0.f) : 0.f;
          v.w = drop_keep(k0, k1, j0 + 3) ? fmaxf(v.w * 1.25f, 0.f) : 0.f;
        }
        *reinterpret_cast<float4*>(&C[(size_t)row * N + col]) = v;
      }
    }
  }
}

// ------------------------- GEMM 128x64 (final layer) -------------------------
__global__ __launch_bounds__(256) void k_gemm_f(const float* __restrict__ A,
                                                const float* __restrict__ B,
                                                const float* __restrict__ sb,
                                                float* __restrict__ C,
                                                int M, int N, int K) {
  const int BM = 128, BK = 16;
  __shared__ float As[BK][BM + 4];
  __shared__ float Bs[BK][64];
  int tid = threadIdx.x;
  int bm = blockIdx.x * BM;

  int la_k4 = (tid & 3) * 4;
  int la_m  = tid >> 2;
  int lb_k  = tid >> 4;
  int lb_n4 = (tid & 15) * 4;
  int tx = tid & 15, ty = tid >> 4;

  float acc[8][4] = {};

  for (int kk = 0; kk < K; kk += BK) {
#pragma unroll
    for (int i = 0; i < 2; ++i) {
      int row = bm + la_m + i * 64;
      float4 a = (row < M) ? *(const float4*)&A[(size_t)row * K + kk + la_k4]
                           : make_float4(0.f, 0.f, 0.f, 0.f);
      As[la_k4 + 0][la_m + i * 64] = a.x;
      As[la_k4 + 1][la_m + i * 64] = a.y;
      As[la_k4 + 2][la_m + i * 64] = a.z;
      As[la_k4 + 3][la_m + i * 64] = a.w;
    }
    *(float4*)&Bs[lb_k][lb_n4] = *(const float4*)&B[(size_t)(kk + lb_k) * N + lb_n4];
    __syncthreads();
#pragma unroll
    for (int k = 0; k < BK; ++k) {
      float4 a0 = *(const float4*)&As[k][ty * 8];
      float4 a1 = *(const float4*)&As[k][ty * 8 + 4];
      float4 b  = *(const float4*)&Bs[k][tx * 4];
      float av[8] = {a0.x, a0.y, a0.z, a0.w, a1.x, a1.y, a1.z, a1.w};
      float bv[4] = {b.x, b.y, b.z, b.w};
#pragma unroll
      for (int i = 0; i < 8; ++i)
#pragma unroll
        for (int j = 0; j < 4; ++j) acc[i][j] += av[i] * bv[j];
    }
    __syncthreads();
  }

#pragma unroll
  for (int i = 0; i < 8; ++i) {
    int row = bm + ty * 8 + i;
    if (row >= M) continue;
    int col = tx * 4;
    float4 v = make_float4(acc[i][0] + sb[col], acc[i][1] + sb[col + 1],
                           acc[i][2] + sb[col + 2], acc[i][3] + sb[col + 3]);
    *reinterpret_cast<float4*>(&C[(size_t)row * N + col]) = v;
  }
}

// ------------------------- layer-1 aggregation: 4-way MLP unroll -------------------
// out[t] = dinv[t] * ( x[t]*dinv[t] + sum_{s} x[s]*dinv[s] )
__global__ __launch_bounds__(256) void k_agg_x(const float* __restrict__ x,
                                               const float* __restrict__ dinv,
                                               const int* __restrict__ row_start,
                                               const int* __restrict__ csr_src,
                                               float* __restrict__ out, int n) {
  const int F = 128;
  int wid = (int)((blockIdx.x * 256 + threadIdx.x) >> 6);
  if (wid >= n) return;
  int lane = threadIdx.x & 63;
  int t = wid;
  float dt = dinv[t];
  float2 xt = ((const float2*)(x + (size_t)t * F))[lane];
  float2 a0 = make_float2(xt.x * dt, xt.y * dt);
  float2 a1 = make_float2(0.f, 0.f), a2 = make_float2(0.f, 0.f), a3 = make_float2(0.f, 0.f);
  int e0 = row_start[t], e1 = row_start[t + 1];
  int e = e0;
  for (; e + 4 <= e1; e += 4) {
    int s0 = csr_src[e], s1 = csr_src[e + 1], s2 = csr_src[e + 2], s3 = csr_src[e + 3];
    float d0 = dinv[s0], d1 = dinv[s1], d2 = dinv[s2], d3 = dinv[s3];
    float2 v0 = ((const float2*)(x + (size_t)s0 * F))[lane];
    float2 v1 = ((const float2*)(x + (size_t)s1 * F))[lane];
    float2 v2 = ((const float2*)(x + (size_t)s2 * F))[lane];
    float2 v3 = ((const float2*)(x + (size_t)s3 * F))[lane];
    a0.x += v0.x * d0; a0.y += v0.y * d0;
    a1.x += v1.x * d1; a1.y += v1.y * d1;
    a2.x += v2.x * d2; a2.y += v2.y * d2;
    a3.x += v3.x * d3; a3.y += v3.y * d3;
  }
  for (; e < e1; ++e) {
    int s = csr_src[e];
    float ds = dinv[s];
    float2 v = ((const float2*)(x + (size_t)s * F))[lane];
    a0.x += v.x * ds; a0.y += v.y * ds;
  }
  float accx = (a0.x + a1.x) + (a2.x + a3.x);
  float accy = (a0.y + a1.y) + (a2.y + a3.y);
  ((float2*)out)[(size_t)t * (F / 2) + lane] = make_float2(accx * dt, accy * dt);
}

// ------------------------- layer-2 aggregation + bias + dropout + relu ------------
__global__ __launch_bounds__(256) void k_agg_w(const float* __restrict__ hws,
                                               const float* __restrict__ dinv,
                                               const float* __restrict__ bias,
                                               const int* __restrict__ row_start,
                                               const int* __restrict__ csr_src,
                                               float* __restrict__ out,
                                               uint32_t k0, uint32_t k1, int n) {
  const int F = 128;
  int wid = (int)((blockIdx.x * 256 + threadIdx.x) >> 6);
  if (wid >= n) return;
  int lane = threadIdx.x & 63;
  int t = wid;
  float2 a0 = ((const float2*)(hws + (size_t)t * F))[lane];
  float2 a1 = make_float2(0.f, 0.f), a2 = make_float2(0.f, 0.f), a3 = make_float2(0.f, 0.f);
  int e0 = row_start[t], e1 = row_start[t + 1];
  int e = e0;
  for (; e + 4 <= e1; e += 4) {
    int s0 = csr_src[e], s1 = csr_src[e + 1], s2 = csr_src[e + 2], s3 = csr_src[e + 3];
    float2 v0 = ((const float2*)(hws + (size_t)s0 * F))[lane];
    float2 v1 = ((const float2*)(hws + (size_t)s1 * F))[lane];
    float2 v2 = ((const float2*)(hws + (size_t)s2 * F))[lane];
    float2 v3 = ((const float2*)(hws + (size_t)s3 * F))[lane];
    a0.x += v0.x; a0.y += v0.y;
    a1.x += v1.x; a1.y += v1.y;
    a2.x += v2.x; a2.y += v2.y;
    a3.x += v3.x; a3.y += v3.y;
  }
  for (; e < e1; ++e) {
    int s = csr_src[e];
    float2 v = ((const float2*)(hws + (size_t)s * F))[lane];
    a0.x += v.x; a0.y += v.y;
  }
  float accx = (a0.x + a1.x) + (a2.x + a3.x);
  float accy = (a0.y + a1.y) + (a2.y + a3.y);
  float d = dinv[t];
  size_t base = (size_t)t * F + lane * 2;
  float vx = accx * d + bias[lane * 2];
  float vy = accy * d + bias[lane * 2 + 1];
  uint32_t j = (uint32_t)base;
  vx = drop_keep(k0, k1, j)     ? fmaxf(vx * 1.25f, 0.f) : 0.f;
  vy = drop_keep(k0, k1, j + 1) ? fmaxf(vy * 1.25f, 0.f) : 0.f;
  ((float2*)out)[base >> 1] = make_float2(vx, vy);
}

// ------------------------- launch -------------------------
static inline size_t ws_align(size_t x) { return (x + 255) & ~(size_t)255; }

extern "C" void kernel_launch(void* const* d_in, const int* in_sizes, int n_in,
                              void* d_out, int out_size, void* d_ws, size_t ws_size,
                              hipStream_t stream) {
  const float* x  = (const float*)d_in[0];
  const float* W1 = (const float*)d_in[1];
  const float* b1 = (const float*)d_in[2];
  const float* W2 = (const float*)d_in[3];
  const float* b2 = (const float*)d_in[4];
  const float* W3 = (const float*)d_in[5];
  const float* b3 = (const float*)d_in[6];
  const int*   ei = (const int*)d_in[7];

  const int IN = 128, H2 = 256, HID = 128, OD = 64;
  const int n = in_sizes[0] / IN;   // 50000
  const int E = in_sizes[7] / 2;    // 800000
  const int* esrc = ei;
  const int* etgt = ei + E;
  const int nb = (n + 255) / 256;

  char* w = (char*)d_ws;
  size_t off = 0;
  auto alloc = [&](size_t bytes) { void* p = w + off; off += ws_align(bytes); return p; };
  float* dinv      = (float*)alloc((size_t)n * 4);
  int*   cnt       = (int*)alloc((size_t)n * 4);
  int*   cursor    = (int*)alloc((size_t)n * 4);
  int*   row_start = (int*)alloc(((size_t)n + 1) * 4);
  int*   bsum      = (int*)alloc(256 * 4);
  int*   bbase     = (int*)alloc(256 * 4);
  int*   csr_src   = (int*)alloc((size_t)E * 4);
  float* bufS      = (float*)alloc((size_t)n * IN * 4);
  float* bufG      = (float*)alloc((size_t)n * IN * 4);
  float* bufH1     = (float*)alloc((size_t)n * H2 * 4);
  (void)ws_size;

  uint32_t dk1_0, dk1_1, dk2_0, dk2_1;
  threefry2x32(0u, 42u, 0u, 0u, dk1_0, dk1_1);
  threefry2x32(0u, 42u, 0u, 1u, dk2_0, dk2_1);

  hipMemsetAsync(cnt, 0, (size_t)n * 4, stream);
  hipMemsetAsync(cursor, 0, (size_t)n * 4, stream);
  k_hist<<<(E + 255) / 256, 256, 0, stream>>>(etgt, cnt, E);
  k_scan1<<<nb, 256, 0, stream>>>(cnt, row_start, bsum, dinv, n);
  k_scan2<<<1, 256, 0, stream>>>(bsum, bbase, row_start, nb, n);
  k_scan3<<<nb, 256, 0, stream>>>(row_start, bbase, n);
  k_scatter<<<(E + 255) / 256, 256, 0, stream>>>(esrc, etgt, row_start, cursor, csr_src, E);

  // layer 1: aggregate-first
  k_agg_x<<<(n + 3) / 4, 256, 0, stream>>>(x, dinv, row_start, csr_src, bufS, n);
  dim3 g1((n + 127) / 128, H2 / 128);
  k_gemm2<2><<<g1, 256, 0, stream>>>(bufS, W1, b1, bufH1, n, H2, IN, dk1_0, dk1_1);

  // layer 2: transform-first
  dim3 g2((n + 127) / 128, HID / 128);
  k_gemm2<0><<<g2, 256, 0, stream>>>(bufH1, W2, dinv, bufS, n, HID, H2, 0u, 0u);
  k_agg_w<<<(n + 3) / 4, 256, 0, stream>>>(bufS, dinv, b2, row_start, csr_src,
                                           bufG, dk2_0, dk2_1, n);

  // layer 3
  k_gemm_f<<<(n + 127) / 128, 256, 0, stream>>>(bufG, W3, b3, (float*)d_out, n, OD, HID);
}

// Round 5
// 317.614 us; speedup vs baseline: 2.0963x; 1.1647x over previous
//
#include <hip/hip_runtime.h>
#include <stdint.h>

// ---------------------------------------------------------------------------
// GCN 3-layer forward, MI355X. Round 5: split-bf16 MFMA GEMMs.
//   fp32 A = A_hi(bf16) + A_lo(bf16);  C = Ah*Bh + Ah*Bl + Al*Bh (fp32 acc)
//   -> uses matrix cores (2.4 PF ceiling) instead of 157 TF fp32 VALU.
// Producers write hi/lo directly (agg1 -> A1, gemm1 epilogue -> h1, agg2 -> A3).
// Weights transposed+split once per launch (k_cvtW).
// MFMA: 16x16x32 bf16; C/D layout col=lane&15, row=(lane>>4)*4+reg (m89-verified).
// ---------------------------------------------------------------------------

typedef __attribute__((ext_vector_type(8))) short s8v;   // 8 bf16 (4 VGPR)
typedef __attribute__((ext_vector_type(4))) float f4v;   // 4 f32 acc

__device__ __host__ __forceinline__ uint32_t tf_rotl(uint32_t v, int r) {
  return (v << r) | (v >> (32 - r));
}

__device__ __host__ __forceinline__ void threefry2x32(uint32_t k0, uint32_t k1,
                                                      uint32_t x0, uint32_t x1,
                                                      uint32_t& o0, uint32_t& o1) {
  const uint32_t k2 = k0 ^ k1 ^ 0x1BD11BDAu;
  x0 += k0; x1 += k1;
#define TFR(r) { x0 += x1; x1 = tf_rotl(x1, r); x1 ^= x0; }
  TFR(13) TFR(15) TFR(26) TFR(6)
  x0 += k1; x1 += k2 + 1u;
  TFR(17) TFR(29) TFR(16) TFR(24)
  x0 += k2; x1 += k0 + 2u;
  TFR(13) TFR(15) TFR(26) TFR(6)
  x0 += k0; x1 += k1 + 3u;
  TFR(17) TFR(29) TFR(16) TFR(24)
  x0 += k1; x1 += k2 + 4u;
  TFR(13) TFR(15) TFR(26) TFR(6)
  x0 += k2; x1 += k0 + 5u;
#undef TFR
  o0 = x0; o1 = x1;
}

__device__ __forceinline__ bool drop_keep(uint32_t k0, uint32_t k1, uint32_t j) {
  uint32_t a, b;
  threefry2x32(k0, k1, 0u, j, a, b);
  uint32_t bits = a ^ b;
  float u = __uint_as_float((bits >> 9) | 0x3f800000u) - 1.0f;
  return u < 0.8f;
}

// fp32 -> bf16 (RNE) and back
__device__ __forceinline__ uint16_t f2bf(float f) {
  uint32_t u = __float_as_uint(f);
  return (uint16_t)((u + 0x7FFFu + ((u >> 16) & 1u)) >> 16);
}
__device__ __forceinline__ float bf2f(uint16_t h) {
  return __uint_as_float((uint32_t)h << 16);
}

// ------------------------- CSR build -------------------------
__global__ void k_hist(const int* __restrict__ tgt, int* __restrict__ cnt, int E) {
  int e = blockIdx.x * 256 + threadIdx.x;
  if (e < E) atomicAdd(&cnt[tgt[e]], 1);
}

__global__ __launch_bounds__(256) void k_scan1(const int* __restrict__ cnt,
                                               int* __restrict__ row_start,
                                               int* __restrict__ bsum,
                                               float* __restrict__ dinv, int n) {
  int tid = threadIdx.x;
  int i = blockIdx.x * 256 + tid;
  int c = (i < n) ? cnt[i] : 0;
  if (i < n) dinv[i] = rsqrtf((float)(c + 1));  // +1 self-loop
  int lane = tid & 63, wv = tid >> 6;
  int v = c;
#pragma unroll
  for (int d = 1; d < 64; d <<= 1) {
    int u = __shfl_up(v, d);
    if (lane >= d) v += u;
  }
  __shared__ int ws[4];
  if (lane == 63) ws[wv] = v;
  __syncthreads();
  int add = 0;
#pragma unroll
  for (int w = 0; w < 4; ++w)
    if (w < wv) add += ws[w];
  int incl = v + add;
  if (i < n) row_start[i] = incl - c;
  if (tid == 255) bsum[blockIdx.x] = incl;
}

__global__ __launch_bounds__(256) void k_scan2(const int* __restrict__ bsum,
                                               int* __restrict__ bbase,
                                               int* __restrict__ row_start,
                                               int nb, int n) {
  int tid = threadIdx.x;
  int c = (tid < nb) ? bsum[tid] : 0;
  int lane = tid & 63, wv = tid >> 6;
  int v = c;
#pragma unroll
  for (int d = 1; d < 64; d <<= 1) {
    int u = __shfl_up(v, d);
    if (lane >= d) v += u;
  }
  __shared__ int ws[4];
  if (lane == 63) ws[wv] = v;
  __syncthreads();
  int add = 0;
#pragma unroll
  for (int w = 0; w < 4; ++w)
    if (w < wv) add += ws[w];
  int incl = v + add;
  if (tid < nb) bbase[tid] = incl - c;
  if (tid == 255) row_start[n] = incl;
}

__global__ void k_scan3(int* __restrict__ row_start, const int* __restrict__ bbase, int n) {
  int i = blockIdx.x * 256 + threadIdx.x;
  if (i < n) row_start[i] += bbase[blockIdx.x];
}

__global__ void k_scatter(const int* __restrict__ src, const int* __restrict__ tgt,
                          const int* __restrict__ row_start, int* __restrict__ cursor,
                          int* __restrict__ csr_src, int E) {
  int e = blockIdx.x * 256 + threadIdx.x;
  if (e >= E) return;
  int t = tgt[e];
  int pos = atomicAdd(&cursor[t], 1);
  csr_src[row_start[t] + pos] = src[e];
}

// ------------------------- weight transpose + hi/lo split -------------------------
// W[K][N] fp32 -> Wt_hi[N][K], Wt_lo[N][K] bf16
__global__ void k_cvtW(const float* __restrict__ W, uint16_t* __restrict__ Wth,
                       uint16_t* __restrict__ Wtl, int K, int N) {
  int i = blockIdx.x * 256 + threadIdx.x;
  if (i >= N * K) return;
  int nn = i / K, kk = i - nn * K;
  float v = W[(size_t)kk * N + nn];
  uint16_t h = f2bf(v);
  Wth[i] = h;
  Wtl[i] = f2bf(v - bf2f(h));
}

// ------------------------- split-bf16 MFMA GEMM -------------------------
// C[M][N] = (Ah+Al)[M][K] x (Bh+Bl)[K][N], B given transposed [N][K].
// BM=128, BN=N_REP*32, BK=32. 4 waves (2x2), wave tile 64 x (BN/2).
// MODE 0: Cf = acc * sb[row]           (dinv row scale, fp32 out)
// MODE 1: Cf = acc + sb[col]           (bias, fp32 out -> d_out)
// MODE 2: hi/lo(relu(drop(acc+sb[col]))) (layer-1 epilogue, bf16 pair out)
template <int N_REP, int MODE>
__global__ __launch_bounds__(256) void k_mfma(
    const uint16_t* __restrict__ Ah, const uint16_t* __restrict__ Al,
    const uint16_t* __restrict__ Bh, const uint16_t* __restrict__ Bl,
    const float* __restrict__ sb, float* __restrict__ Cf,
    uint16_t* __restrict__ Chi, uint16_t* __restrict__ Clo,
    int M, int N, int K, uint32_t k0, uint32_t k1) {
  const int BM = 128, BK = 32, BN = N_REP * 32;
  __shared__ uint16_t lA[2][BM][BK];  // [hi/lo][row][k]  rows of 64B
  __shared__ uint16_t lB[2][BN][BK];
  int tid = threadIdx.x;
  int lane = tid & 63;
  int wid = tid >> 6;
  int wm = wid & 1, wn = wid >> 1;  // 2x2 wave grid
  int bm = blockIdx.x * BM, bn = blockIdx.y * BN;

  f4v acc[4][N_REP] = {};

  for (int kk = 0; kk < K; kk += BK) {
    // stage A (128x32 hi+lo): i = tid + p*256 -> row=i>>2, seg=i&3 (conflict-free writes)
#pragma unroll
    for (int p = 0; p < 2; ++p) {
      int i = tid + p * 256;
      int row = i >> 2, seg = i & 3;
      size_t ga = (size_t)(bm + row) * K + kk + seg * 8;
      *(uint4*)&lA[0][row][seg * 8] = *(const uint4*)&Ah[ga];
      *(uint4*)&lA[1][row][seg * 8] = *(const uint4*)&Al[ga];
    }
#pragma unroll
    for (int p = 0; p < BN / 64; ++p) {
      int i = tid + p * 256;
      int row = i >> 2, seg = i & 3;
      size_t gb = (size_t)(bn + row) * K + kk + seg * 8;
      *(uint4*)&lB[0][row][seg * 8] = *(const uint4*)&Bh[gb];
      *(uint4*)&lB[1][row][seg * 8] = *(const uint4*)&Bl[gb];
    }
    __syncthreads();

    int r16 = lane & 15, kg = (lane >> 4) * 8;
    s8v ah[4], al[4], bh[N_REP], bl[N_REP];
#pragma unroll
    for (int mb = 0; mb < 4; ++mb) {
      ah[mb] = *(const s8v*)&lA[0][wm * 64 + mb * 16 + r16][kg];
      al[mb] = *(const s8v*)&lA[1][wm * 64 + mb * 16 + r16][kg];
    }
#pragma unroll
    for (int nb = 0; nb < N_REP; ++nb) {
      bh[nb] = *(const s8v*)&lB[0][wn * (BN / 2) + nb * 16 + r16][kg];
      bl[nb] = *(const s8v*)&lB[1][wn * (BN / 2) + nb * 16 + r16][kg];
    }
#pragma unroll
    for (int mb = 0; mb < 4; ++mb)
#pragma unroll
      for (int nb = 0; nb < N_REP; ++nb) {
        acc[mb][nb] = __builtin_amdgcn_mfma_f32_16x16x32_bf16(ah[mb], bh[nb], acc[mb][nb], 0, 0, 0);
        acc[mb][nb] = __builtin_amdgcn_mfma_f32_16x16x32_bf16(ah[mb], bl[nb], acc[mb][nb], 0, 0, 0);
        acc[mb][nb] = __builtin_amdgcn_mfma_f32_16x16x32_bf16(al[mb], bh[nb], acc[mb][nb], 0, 0, 0);
      }
    __syncthreads();
  }

#pragma unroll
  for (int mb = 0; mb < 4; ++mb) {
#pragma unroll
    for (int nb = 0; nb < N_REP; ++nb) {
#pragma unroll
      for (int r = 0; r < 4; ++r) {
        int row = bm + wm * 64 + mb * 16 + (lane >> 4) * 4 + r;
        int col = bn + wn * (BN / 2) + nb * 16 + (lane & 15);
        if (row >= M) continue;
        float v = acc[mb][nb][r];
        size_t o = (size_t)row * N + col;
        if (MODE == 0) {
          Cf[o] = v * sb[row];
        } else if (MODE == 1) {
          Cf[o] = v + sb[col];
        } else {
          v += sb[col];
          uint32_t j = (uint32_t)row * (uint32_t)N + (uint32_t)col;
          v = drop_keep(k0, k1, j) ? fmaxf(v * 1.25f, 0.f) : 0.f;
          uint16_t h = f2bf(v);
          Chi[o] = h;
          Clo[o] = f2bf(v - bf2f(h));
        }
      }
    }
  }
}

// ------------------------- layer-1 aggregation -> bf16 hi/lo -------------------
// out[t] = dinv[t] * ( x[t]*dinv[t] + sum_{s} x[s]*dinv[s] ), 4-way MLP unroll
__global__ __launch_bounds__(256) void k_agg_x(const float* __restrict__ x,
                                               const float* __restrict__ dinv,
                                               const int* __restrict__ row_start,
                                               const int* __restrict__ csr_src,
                                               uint32_t* __restrict__ outh,
                                               uint32_t* __restrict__ outl, int n) {
  const int F = 128;
  int wid = (int)((blockIdx.x * 256 + threadIdx.x) >> 6);
  if (wid >= n) return;
  int lane = threadIdx.x & 63;
  int t = wid;
  float dt = dinv[t];
  float2 xt = ((const float2*)(x + (size_t)t * F))[lane];
  float2 a0 = make_float2(xt.x * dt, xt.y * dt);
  float2 a1 = make_float2(0.f, 0.f), a2 = make_float2(0.f, 0.f), a3 = make_float2(0.f, 0.f);
  int e0 = row_start[t], e1 = row_start[t + 1];
  int e = e0;
  for (; e + 4 <= e1; e += 4) {
    int s0 = csr_src[e], s1 = csr_src[e + 1], s2 = csr_src[e + 2], s3 = csr_src[e + 3];
    float d0 = dinv[s0], d1 = dinv[s1], d2 = dinv[s2], d3 = dinv[s3];
    float2 v0 = ((const float2*)(x + (size_t)s0 * F))[lane];
    float2 v1 = ((const float2*)(x + (size_t)s1 * F))[lane];
    float2 v2 = ((const float2*)(x + (size_t)s2 * F))[lane];
    float2 v3 = ((const float2*)(x + (size_t)s3 * F))[lane];
    a0.x += v0.x * d0; a0.y += v0.y * d0;
    a1.x += v1.x * d1; a1.y += v1.y * d1;
    a2.x += v2.x * d2; a2.y += v2.y * d2;
    a3.x += v3.x * d3; a3.y += v3.y * d3;
  }
  for (; e < e1; ++e) {
    int s = csr_src[e];
    float ds = dinv[s];
    float2 v = ((const float2*)(x + (size_t)s * F))[lane];
    a0.x += v.x * ds; a0.y += v.y * ds;
  }
  float rx = ((a0.x + a1.x) + (a2.x + a3.x)) * dt;
  float ry = ((a0.y + a1.y) + (a2.y + a3.y)) * dt;
  uint16_t hx = f2bf(rx), hy = f2bf(ry);
  uint16_t lx = f2bf(rx - bf2f(hx)), ly = f2bf(ry - bf2f(hy));
  outh[(size_t)t * 64 + lane] = (uint32_t)hx | ((uint32_t)hy << 16);
  outl[(size_t)t * 64 + lane] = (uint32_t)lx | ((uint32_t)ly << 16);
}

// ------------------------- layer-2 aggregation + bias + dropout + relu -> hi/lo ---
__global__ __launch_bounds__(256) void k_agg_w(const float* __restrict__ hws,
                                               const float* __restrict__ dinv,
                                               const float* __restrict__ bias,
                                               const int* __restrict__ row_start,
                                               const int* __restrict__ csr_src,
                                               uint32_t* __restrict__ outh,
                                               uint32_t* __restrict__ outl,
                                               uint32_t k0, uint32_t k1, int n) {
  const int F = 128;
  int wid = (int)((blockIdx.x * 256 + threadIdx.x) >> 6);
  if (wid >= n) return;
  int lane = threadIdx.x & 63;
  int t = wid;
  float2 a0 = ((const float2*)(hws + (size_t)t * F))[lane];
  float2 a1 = make_float2(0.f, 0.f), a2 = make_float2(0.f, 0.f), a3 = make_float2(0.f, 0.f);
  int e0 = row_start[t], e1 = row_start[t + 1];
  int e = e0;
  for (; e + 4 <= e1; e += 4) {
    int s0 = csr_src[e], s1 = csr_src[e + 1], s2 = csr_src[e + 2], s3 = csr_src[e + 3];
    float2 v0 = ((const float2*)(hws + (size_t)s0 * F))[lane];
    float2 v1 = ((const float2*)(hws + (size_t)s1 * F))[lane];
    float2 v2 = ((const float2*)(hws + (size_t)s2 * F))[lane];
    float2 v3 = ((const float2*)(hws + (size_t)s3 * F))[lane];
    a0.x += v0.x; a0.y += v0.y;
    a1.x += v1.x; a1.y += v1.y;
    a2.x += v2.x; a2.y += v2.y;
    a3.x += v3.x; a3.y += v3.y;
  }
  for (; e < e1; ++e) {
    int s = csr_src[e];
    float2 v = ((const float2*)(hws + (size_t)s * F))[lane];
    a0.x += v.x; a0.y += v.y;
  }
  float d = dinv[t];
  float vx = ((a0.x + a1.x) + (a2.x + a3.x)) * d + bias[lane * 2];
  float vy = ((a0.y + a1.y) + (a2.y + a3.y)) * d + bias[lane * 2 + 1];
  uint32_t j = (uint32_t)t * 128u + (uint32_t)lane * 2u;
  vx = drop_keep(k0, k1, j)     ? fmaxf(vx * 1.25f, 0.f) : 0.f;
  vy = drop_keep(k0, k1, j + 1) ? fmaxf(vy * 1.25f, 0.f) : 0.f;
  uint16_t hx = f2bf(vx), hy = f2bf(vy);
  uint16_t lx = f2bf(vx - bf2f(hx)), ly = f2bf(vy - bf2f(hy));
  outh[(size_t)t * 64 + lane] = (uint32_t)hx | ((uint32_t)hy << 16);
  outl[(size_t)t * 64 + lane] = (uint32_t)lx | ((uint32_t)ly << 16);
}

// ------------------------- launch -------------------------
static inline size_t ws_align(size_t x) { return (x + 255) & ~(size_t)255; }

extern "C" void kernel_launch(void* const* d_in, const int* in_sizes, int n_in,
                              void* d_out, int out_size, void* d_ws, size_t ws_size,
                              hipStream_t stream) {
  const float* x  = (const float*)d_in[0];
  const float* W1 = (const float*)d_in[1];
  const float* b1 = (const float*)d_in[2];
  const float* W2 = (const float*)d_in[3];
  const float* b2 = (const float*)d_in[4];
  const float* W3 = (const float*)d_in[5];
  const float* b3 = (const float*)d_in[6];
  const int*   ei = (const int*)d_in[7];

  const int IN = 128, H2 = 256, HID = 128, OD = 64;
  const int n = in_sizes[0] / IN;   // 50000
  const int E = in_sizes[7] / 2;    // 800000
  const int* esrc = ei;
  const int* etgt = ei + E;
  const int nb = (n + 255) / 256;
  const int Mb = (n + 127) / 128;       // 391 row-blocks
  const int Mpad = Mb * 128;            // 50048

  char* w = (char*)d_ws;
  size_t off = 0;
  auto alloc = [&](size_t bytes) { void* p = w + off; off += ws_align(bytes); return p; };
  float*    dinv      = (float*)alloc((size_t)n * 4);
  int*      cnt       = (int*)alloc((size_t)n * 4);
  int*      cursor    = (int*)alloc((size_t)n * 4);
  int*      row_start = (int*)alloc(((size_t)n + 1) * 4);
  int*      bsum      = (int*)alloc(256 * 4);
  int*      bbase     = (int*)alloc(256 * 4);
  int*      csr_src   = (int*)alloc((size_t)E * 4);
  uint16_t* A1h       = (uint16_t*)alloc((size_t)Mpad * IN * 2);   // also A3 (aliased)
  uint16_t* A1l       = (uint16_t*)alloc((size_t)Mpad * IN * 2);
  uint16_t* h1h       = (uint16_t*)alloc((size_t)Mpad * H2 * 2);
  uint16_t* h1l       = (uint16_t*)alloc((size_t)Mpad * H2 * 2);
  float*    hw2       = (float*)alloc((size_t)n * HID * 4);
  uint16_t* Wt1h      = (uint16_t*)alloc((size_t)H2 * IN * 2);
  uint16_t* Wt1l      = (uint16_t*)alloc((size_t)H2 * IN * 2);
  uint16_t* Wt2h      = (uint16_t*)alloc((size_t)HID * H2 * 2);
  uint16_t* Wt2l      = (uint16_t*)alloc((size_t)HID * H2 * 2);
  uint16_t* Wt3h      = (uint16_t*)alloc((size_t)OD * IN * 2);
  uint16_t* Wt3l      = (uint16_t*)alloc((size_t)OD * IN * 2);
  (void)ws_size;

  uint32_t dk1_0, dk1_1, dk2_0, dk2_1;
  threefry2x32(0u, 42u, 0u, 0u, dk1_0, dk1_1);
  threefry2x32(0u, 42u, 0u, 1u, dk2_0, dk2_1);

  // zero pads (rows n..Mpad) so OOB tile rows contribute 0 / no NaN
  int padrows = Mpad - n;
  hipMemsetAsync(A1h + (size_t)n * IN, 0, (size_t)padrows * IN * 2, stream);
  hipMemsetAsync(A1l + (size_t)n * IN, 0, (size_t)padrows * IN * 2, stream);
  hipMemsetAsync(h1h + (size_t)n * H2, 0, (size_t)padrows * H2 * 2, stream);
  hipMemsetAsync(h1l + (size_t)n * H2, 0, (size_t)padrows * H2 * 2, stream);
  hipMemsetAsync(cnt, 0, (size_t)n * 4, stream);
  hipMemsetAsync(cursor, 0, (size_t)n * 4, stream);

  // weights: transpose + split
  k_cvtW<<<(H2 * IN + 255) / 256, 256, 0, stream>>>(W1, Wt1h, Wt1l, IN, H2);
  k_cvtW<<<(HID * H2 + 255) / 256, 256, 0, stream>>>(W2, Wt2h, Wt2l, H2, HID);
  k_cvtW<<<(OD * IN + 255) / 256, 256, 0, stream>>>(W3, Wt3h, Wt3l, IN, OD);

  // CSR
  k_hist<<<(E + 255) / 256, 256, 0, stream>>>(etgt, cnt, E);
  k_scan1<<<nb, 256, 0, stream>>>(cnt, row_start, bsum, dinv, n);
  k_scan2<<<1, 256, 0, stream>>>(bsum, bbase, row_start, nb, n);
  k_scan3<<<nb, 256, 0, stream>>>(row_start, bbase, n);
  k_scatter<<<(E + 255) / 256, 256, 0, stream>>>(esrc, etgt, row_start, cursor, csr_src, E);

  // layer 1: aggregate-first, then MFMA GEMM with fused bias+drop+relu -> h1 hi/lo
  k_agg_x<<<(n + 3) / 4, 256, 0, stream>>>(x, dinv, row_start, csr_src,
                                           (uint32_t*)A1h, (uint32_t*)A1l, n);
  {
    dim3 g(Mb, H2 / 128);
    k_mfma<4, 2><<<g, 256, 0, stream>>>(A1h, A1l, Wt1h, Wt1l, b1, nullptr, h1h, h1l,
                                        n, H2, IN, dk1_0, dk1_1);
  }

  // layer 2: hw2 = (h1 @ W2) * dinv[row]; aggregate -> A3 hi/lo (aliases A1)
  {
    dim3 g(Mb, HID / 128);
    k_mfma<4, 0><<<g, 256, 0, stream>>>(h1h, h1l, Wt2h, Wt2l, dinv, hw2, nullptr, nullptr,
                                        n, HID, H2, 0u, 0u);
  }
  k_agg_w<<<(n + 3) / 4, 256, 0, stream>>>(hw2, dinv, b2, row_start, csr_src,
                                           (uint32_t*)A1h, (uint32_t*)A1l, dk2_0, dk2_1, n);

  // layer 3: d_out = h2 @ W3 + b3
  {
    dim3 g(Mb, OD / 64);
    k_mfma<2, 1><<<g, 256, 0, stream>>>(A1h, A1l, Wt3h, Wt3l, b3, (float*)d_out,
                                        nullptr, nullptr, n, OD, IN, 0u, 0u);
  }
}